// Round 1
// 380.178 us; speedup vs baseline: 1.0026x; 1.0026x over previous
//
#include <hip/hip_runtime.h>

#define DM    1024
#define HID   4096
#define NKEYS 65536
#define TOPK  6
#define NEGF  (-3.4e38f)

#define SBLK  2048               // score blocks
#define RPB   (NKEYS / SBLK)     // 32 rows per block
#define RPW   (RPB / 4)          // 8 rows per wave
#define NC    (SBLK * TOPK)      // 12288 candidates

typedef float fvec4 __attribute__((ext_vector_type(4)));

__device__ __forceinline__ fvec4 nt_load4(const float* p) {
    return __builtin_nontemporal_load((const fvec4*)p);
}

// ---- kernel 1: fused q-projection + v-partial -------------------------------
// 256 blocks x 256 threads. Block b owns h-rows [16b, 16b+16).
// Phase A: 4 waves compute 4 q-rows each (wave-per-row dot over Wq) -> LDS.
//          query fragment hoisted to 4 VGPR vec4s (was reloaded per row).
// Phase B: v_part[b][d] = sum_j qs[j] * Wk[h0+j][d], thread t owns cols 4t..4t+3.
__global__ __launch_bounds__(256) void proj_fused_kernel(const float* __restrict__ Wq,
                                                         const float* __restrict__ query,
                                                         const float* __restrict__ bq,
                                                         const float* __restrict__ Wk,
                                                         float* __restrict__ v_part) {
    const int t = threadIdx.x, b = blockIdx.x;
    const int wave = t >> 6, lane = t & 63;
    const int h0 = b * 16;
    __shared__ float qs[16];

    const fvec4* __restrict__ qv = (const fvec4*)query;
    fvec4 xq[4];
#pragma unroll
    for (int k = 0; k < 4; ++k) xq[k] = qv[lane + k * 64];

#pragma unroll
    for (int j = 0; j < 4; ++j) {
        const int h = h0 + wave * 4 + j;
        const float* Wrow = Wq + (size_t)h * DM;
        float acc = 0.f;
#pragma unroll
        for (int k = 0; k < 4; ++k) {
            fvec4 w = nt_load4(Wrow + (lane + k * 64) * 4);
            acc += w.x * xq[k].x + w.y * xq[k].y + w.z * xq[k].z + w.w * xq[k].w;
        }
#pragma unroll
        for (int off = 32; off > 0; off >>= 1) acc += __shfl_down(acc, off);
        if (lane == 0) qs[wave * 4 + j] = acc + bq[h];
    }
    __syncthreads();

    fvec4 acc4 = {0.f, 0.f, 0.f, 0.f};
#pragma unroll 4
    for (int j = 0; j < 16; ++j) {
        fvec4 w = nt_load4(Wk + (size_t)(h0 + j) * DM + t * 4);
        acc4 += w * qs[j];
    }
    *(fvec4*)(v_part + (size_t)b * DM + t * 4) = acc4;
}

// ---- kernel 2: v[d] = sum_b v_part[b][d]  (16 blocks x 256, 4-way b-split) --
// Was 16x64 (1024 threads total, 256 serial summands/thread). Now each wave
// owns a 64-wide b-quarter; LDS combine. 4x parallelism on a latency-bound op.
__global__ __launch_bounds__(256) void vreduce_kernel(const float* __restrict__ v_part,
                                                      float* __restrict__ v) {
    const int t = threadIdx.x, w = t >> 6, lane = t & 63;
    const int d = blockIdx.x * 64 + lane;
    __shared__ float part[4][64];
    float acc = 0.f;
#pragma unroll 8
    for (int b = w * 64; b < w * 64 + 64; ++b) acc += v_part[(size_t)b * DM + d];
    part[w][lane] = acc;
    __syncthreads();
    if (w == 0) v[d] = part[0][lane] + part[1][lane] + part[2][lane] + part[3][lane];
}

// ---- kernel 3: fused scores + per-block top-6 -------------------------------
// 2048 blocks x 256 threads; block b owns rows [32b, 32b+32), 8 rows/wave.
// v cached in 16 VGPRs per lane (was an L1 reload per row); nt loads kept for
// the 256 MB key_mat stream (R5-vs-R3 experiment: nt wins). The 8-row loop
// gives the scheduler up to 32 outstanding 16B loads/lane. Eliminates the
// scores[] round-trip and the separate topk_stage1 launch.
__global__ __launch_bounds__(256) void score_topk1_kernel(const float* __restrict__ key_mat,
                                                          const float* __restrict__ v,
                                                          float* __restrict__ cand_v,
                                                          int* __restrict__ cand_i) {
    const int t = threadIdx.x, b = blockIdx.x;
    const int wave = t >> 6, lane = t & 63;
    const int r0 = b * RPB + wave * RPW;

    __shared__ float sc[RPB];

    const fvec4* __restrict__ vv = (const fvec4*)v;
    fvec4 vb[4];
#pragma unroll
    for (int k = 0; k < 4; ++k) vb[k] = vv[lane + k * 64];

#pragma unroll
    for (int j = 0; j < RPW; ++j) {
        const float* row = key_mat + (size_t)(r0 + j) * DM;
        float acc = 0.f;
#pragma unroll
        for (int k = 0; k < 4; ++k) {
            fvec4 a = nt_load4(row + (lane + k * 64) * 4);
            acc += a.x * vb[k].x + a.y * vb[k].y + a.z * vb[k].z + a.w * vb[k].w;
        }
#pragma unroll
        for (int off = 32; off > 0; off >>= 1) acc += __shfl_down(acc, off);
        if (lane == 0) sc[wave * RPW + j] = acc;
    }
    __syncthreads();

    // wave 0: top-6 of the block's 32 scores via 6 knockout shfl-reductions.
    if (wave == 0) {
        float val = (lane < RPB) ? sc[lane] : NEGF;
#pragma unroll
        for (int p = 0; p < TOPK; ++p) {
            float m = val; int ml = lane;
#pragma unroll
            for (int off = 32; off > 0; off >>= 1) {
                float ov = __shfl_down(m, off);
                int   ol = __shfl_down(ml, off);
                if (ov > m) { m = ov; ml = ol; }
            }
            if (lane == 0) {
                cand_v[b * TOPK + p] = m;
                cand_i[b * TOPK + p] = b * RPB + ml;
            }
            ml = __shfl(ml, 0);                  // broadcast winner lane
            if (lane == ml) val = NEGF;          // knock out
        }
    }
}

// ---- kernel 4: top-6 of 12288 candidates + mean of selected rows ------------
// Values-only in LDS (48 KB); winner index fetched from global cand_i (6 reads
// total, L2-resident). LDS scan uses pos = j*256 + t: consecutive lanes hit
// consecutive banks (conflict-free).
__global__ __launch_bounds__(256) void topk_stage2_mean(const float* __restrict__ cand_v,
                                                        const int* __restrict__ cand_i,
                                                        const float* __restrict__ key_mat,
                                                        float* __restrict__ out) {
    const int t = threadIdx.x;

    __shared__ float sv[NC];
    __shared__ float wv[4];
    __shared__ int   wi[4];
    __shared__ int   sel[TOPK];

#pragma unroll
    for (int j = 0; j < NC / 256; ++j) sv[j * 256 + t] = cand_v[j * 256 + t];
    __syncthreads();

    for (int p = 0; p < TOPK; ++p) {
        float m = NEGF; int mp = 0;
#pragma unroll
        for (int j = 0; j < NC / 256; ++j) {
            const int pos = j * 256 + t;
            const float val = sv[pos];
            if (val > m) { m = val; mp = pos; }
        }
#pragma unroll
        for (int off = 32; off > 0; off >>= 1) {
            float ov = __shfl_down(m, off);
            int   op = __shfl_down(mp, off);
            if (ov > m) { m = ov; mp = op; }
        }
        const int lane = t & 63, w = t >> 6;
        if (lane == 0) { wv[w] = m; wi[w] = mp; }
        __syncthreads();
        if (t == 0) {
            float bm = wv[0]; int bp = wi[0];
#pragma unroll
            for (int j = 1; j < 4; ++j) if (wv[j] > bm) { bm = wv[j]; bp = wi[j]; }
            sel[p] = cand_i[bp];
            sv[bp] = NEGF;
        }
        __syncthreads();
    }

    fvec4 acc = {0.f, 0.f, 0.f, 0.f};
#pragma unroll
    for (int p = 0; p < TOPK; ++p)
        acc += *(const fvec4*)(key_mat + (size_t)sel[p] * DM + t * 4);
    acc *= (1.0f / 6.0f);
    *(fvec4*)(out + t * 4) = acc;
}

extern "C" void kernel_launch(void* const* d_in, const int* in_sizes, int n_in,
                              void* d_out, int out_size, void* d_ws, size_t ws_size,
                              hipStream_t stream) {
    const float* query   = (const float*)d_in[0];   // [1024]
    const float* key_mat = (const float*)d_in[1];   // [65536, 1024]
    const float* Wq      = (const float*)d_in[2];   // [4096, 1024]
    const float* bq      = (const float*)d_in[3];   // [4096]
    const float* Wk      = (const float*)d_in[4];   // [4096, 1024]
    // bk skipped: bk.q is a uniform score shift -> cannot change top-k ordering
    float* out = (float*)d_out;                     // [1024] f32

    float* ws      = (float*)d_ws;
    float* v_part  = ws;                            // 256*1024
    float* v       = v_part + 256 * DM;             // 1024
    float* cand_v  = v + DM;                        // 12288
    int*   cand_i  = (int*)(cand_v + NC);           // 12288

    proj_fused_kernel <<<256,  256, 0, stream>>>(Wq, query, bq, Wk, v_part);
    vreduce_kernel    <<<16,   256, 0, stream>>>(v_part, v);
    score_topk1_kernel<<<SBLK, 256, 0, stream>>>(key_mat, v, cand_v, cand_i);
    topk_stage2_mean  <<<1,    256, 0, stream>>>(cand_v, cand_i, key_mat, out);
}